// Round 4
// baseline (2484.605 us; speedup 1.0000x reference)
//
#include <hip/hip_runtime.h>

// Problem constants (match reference)
constexpr int   NVEC  = 131072;   // N
constexpr int   DIMC  = 128;      // latent dim
constexpr int   KC    = 4096;     // codebook size
constexpr float DECAYC = 0.99f;
constexpr float OMDECAY = 0.01f;
constexpr float EPSC  = 1e-5f;
constexpr float MARGIN = 0.1f;    // >> worst-case split-bf16 score error (~0.02)

typedef __bf16 v8bf __attribute__((ext_vector_type(8)));
typedef float  v4f  __attribute__((ext_vector_type(4)));

// Async global->LDS 16B copy: dest = wave-uniform LDS base + lane*16.
// Falls back to explicit load+store if the builtin is unavailable.
__device__ __forceinline__ void async_copy16(const void* gp, void* lds_wave_base, int lane) {
#if __has_builtin(__builtin_amdgcn_global_load_lds)
    __builtin_amdgcn_global_load_lds(
        (const __attribute__((address_space(1))) unsigned int*)gp,
        (__attribute__((address_space(3))) unsigned int*)lds_wave_base, 16, 0, 0);
#else
    ((v8bf*)lds_wave_base)[lane] = *(const v8bf*)gp;
#endif
}

// ---------------- kernel S: split embed into bf16 hi/lo (transposed) + fused colnorm ----------------
__global__ __launch_bounds__(256) void split_e_kernel(const float* __restrict__ embed,
                                                      __bf16* __restrict__ ehT,
                                                      __bf16* __restrict__ elT,
                                                      float* __restrict__ nhe2) {
    __shared__ __bf16 sh_h[64 * 130];
    __shared__ __bf16 sh_l[64 * 130];
    __shared__ float  sh_n[4][64];
    const int tid = threadIdx.x;
    const int kbase = blockIdx.x * 64;
    const int kloc = tid & 63;      // fixed per thread across iterations
    float nacc = 0.f;
    for (int it = 0; it < 32; ++it) {
        int d = it * 4 + (tid >> 6);
        float v = embed[(size_t)d * KC + kbase + kloc];   // coalesced in k
        __bf16 h = (__bf16)v;
        __bf16 l = (__bf16)(v - (float)h);
        sh_h[kloc * 130 + d] = h;
        sh_l[kloc * 130 + d] = l;
        nacc = fmaf(v, v, nacc);
    }
    sh_n[tid >> 6][kloc] = nacc;
    __syncthreads();
    if (tid < 64)
        nhe2[kbase + tid] = -0.5f * (sh_n[0][tid] + sh_n[1][tid] + sh_n[2][tid] + sh_n[3][tid]);
    for (int it = 0; it < 32; ++it) {
        int idx = it * 256 + tid;
        int k = idx >> 7;               // 0..63
        int d = idx & 127;
        ehT[(size_t)(kbase + k) * DIMC + d] = sh_h[k * 130 + d];
        elT[(size_t)(kbase + k) * DIMC + d] = sh_l[k * 130 + d];
    }
}

// ---------------- kernel P1 v2: MFMA split-bf16 GEMM + per-row top-2 ----------------
// 4 waves/block; each wave owns 64 rows (4 x 16-row tiles, A frags in registers).
// Embed chunk: 64 cols x 128 k (hi+lo) in LDS as 16B granules with XOR swizzle:
//   granule (col, g) stored at index col*16 + (g ^ (col&7))
// -> staging (via global_load_lds, lane-contiguous) and fragment ds_read_b128
//    both land 8 words/bank (conflict-free balanced).
__global__ __launch_bounds__(256, 2) void phase1_kernel(
    const float* __restrict__ x, const __bf16* __restrict__ ehT,
    const __bf16* __restrict__ elT, const float* __restrict__ nhe2,
    float* __restrict__ out_indf, int* __restrict__ ws_ind, float* __restrict__ ws_gap)
{
    __shared__ v8bf Eh[1024];   // 16 KB
    __shared__ v8bf El[1024];   // 16 KB
    const int tid  = threadIdx.x;
    const int wave = tid >> 6;
    const int lane = tid & 63;
    const int c    = lane & 15;     // MFMA m / n index
    const int q    = lane >> 4;     // quad
    const int rowBase = blockIdx.x * 256 + wave * 64;

    // A fragments: 4 row-tiles x 4 k-slices, hi + exact residual lo (128 VGPRs)
    v8bf ah[4][4], al[4][4];
#pragma unroll
    for (int t = 0; t < 4; ++t)
#pragma unroll
        for (int s = 0; s < 4; ++s) {
            const float* p = x + (size_t)(rowBase + t * 16 + c) * DIMC + s * 32 + q * 8;
            float4 v0 = *reinterpret_cast<const float4*>(p);
            float4 v1 = *reinterpret_cast<const float4*>(p + 4);
            float vv[8] = {v0.x, v0.y, v0.z, v0.w, v1.x, v1.y, v1.z, v1.w};
            v8bf h, l;
#pragma unroll
            for (int j = 0; j < 8; ++j) {
                __bf16 hh = (__bf16)vv[j];
                h[j] = hh;
                l[j] = (__bf16)(vv[j] - (float)hh);
            }
            ah[t][s] = h; al[t][s] = l;
        }

    float b1[16], b2[16]; int i1[16];
#pragma unroll
    for (int s = 0; s < 16; ++s) { b1[s] = -3.4e38f; b2[s] = -3.4e38f; i1[s] = 0; }

    for (int chunk = 0; chunk < KC / 64; ++chunk) {
        const int colChunk = chunk * 64;
        // stage 64 cols x 128 k (hi+lo) via async 16B direct-to-LDS
#pragma unroll
        for (int it = 0; it < 4; ++it) {
            int f   = it * 256 + tid;            // granule index 0..1023
            int col = f >> 4;
            int g   = (f & 15) ^ (col & 7);      // un-swizzled k-granule
            const __bf16* gh = ehT + (size_t)(colChunk + col) * DIMC + g * 8;
            const __bf16* gl = elT + (size_t)(colChunk + col) * DIMC + g * 8;
            async_copy16(gh, &Eh[it * 256 + wave * 64], lane);
            async_copy16(gl, &El[it * 256 + wave * 64], lane);
        }
        __syncthreads();

#pragma unroll
        for (int ct = 0; ct < 4; ++ct) {
            const int colLocal = ct * 16 + c;
            const int swz = colLocal & 7;
            v4f acc[4];
#pragma unroll
            for (int t = 0; t < 4; ++t) acc[t] = v4f{0.f, 0.f, 0.f, 0.f};
#pragma unroll
            for (int s = 0; s < 4; ++s) {
                int gi = colLocal * 16 + ((s * 4 + q) ^ swz);
                v8bf bh = Eh[gi];
                v8bf bl = El[gi];
#pragma unroll
                for (int t = 0; t < 4; ++t)
                    acc[t] = __builtin_amdgcn_mfma_f32_16x16x32_bf16(ah[t][s], bh, acc[t], 0, 0, 0);
#pragma unroll
                for (int t = 0; t < 4; ++t)
                    acc[t] = __builtin_amdgcn_mfma_f32_16x16x32_bf16(al[t][s], bh, acc[t], 0, 0, 0);
#pragma unroll
                for (int t = 0; t < 4; ++t)
                    acc[t] = __builtin_amdgcn_mfma_f32_16x16x32_bf16(ah[t][s], bl, acc[t], 0, 0, 0);
            }
            const int colG = colChunk + colLocal;
            const float nh = nhe2[colG];
#pragma unroll
            for (int t = 0; t < 4; ++t)
#pragma unroll
                for (int r = 0; r < 4; ++r) {
                    int idx = t * 4 + r;
                    float sc = acc[t][r] + nh;
                    float ob1 = b1[idx];
                    bool gt = sc > ob1;                       // strict: ties keep earlier col
                    b2[idx] = fmaxf(b2[idx], fminf(ob1, sc)); // correct 2nd-best both ways
                    b1[idx] = fmaxf(ob1, sc);
                    i1[idx] = gt ? colG : i1[idx];
                }
        }
        __syncthreads();
    }

    // top-2 merge across the 16 col-lanes of each row group (tie -> lowest index)
#pragma unroll
    for (int off = 1; off < 16; off <<= 1) {
#pragma unroll
        for (int s = 0; s < 16; ++s) {
            float ob1 = __shfl_xor(b1[s], off, 64);
            int   oi1 = __shfl_xor(i1[s], off, 64);
            float ob2 = __shfl_xor(b2[s], off, 64);
            if (ob1 > b1[s] || (ob1 == b1[s] && oi1 < i1[s])) {
                b2[s] = fmaxf(b1[s], ob2); b1[s] = ob1; i1[s] = oi1;
            } else {
                b2[s] = fmaxf(b2[s], ob1);
            }
        }
    }
    if (c == 0) {
#pragma unroll
        for (int s = 0; s < 16; ++s) {
            int t = s >> 2, r = s & 3;
            int row = rowBase + t * 16 + q * 4 + r;
            ws_ind[row]   = i1[s];
            out_indf[row] = (float)i1[s];
            ws_gap[row]   = b1[s] - b2[s];
        }
    }
}

// ---------------- kernel F: compact flagged rows (gap < MARGIN) ----------------
__global__ __launch_bounds__(256) void flag_kernel(const float* __restrict__ ws_gap,
                                                   int* __restrict__ ws_nflag,
                                                   int* __restrict__ ws_list) {
    int n = blockIdx.x * 256 + threadIdx.x;
    if (ws_gap[n] < MARGIN) {
        int p = atomicAdd(ws_nflag, 1);
        ws_list[p] = n;
    }
}

// ---------------- kernel R: exact fp32 rescore of flagged rows (16 rows/block) ----------------
// Arithmetic (ascending-d fmaf chain + nhe2 add) matches the round-1 fp32 kernel
// that matched the numpy reference on all rows.
__global__ __launch_bounds__(256) void rescore_kernel(
    const float* __restrict__ x, const float* __restrict__ embed,
    const float* __restrict__ nhe2, const int* __restrict__ ws_list,
    const int* __restrict__ ws_nflag, int* __restrict__ ws_ind,
    float* __restrict__ out_indf)
{
    __shared__ float xs[128][16];
    __shared__ float redv[4][16];
    __shared__ int   redi[4][16];
    const int tid  = threadIdx.x;
    const int lane = tid & 63;
    const int wave = tid >> 6;
    const int nflag = *ws_nflag;

    for (int g = blockIdx.x; g * 16 < nflag; g += gridDim.x) {
        const int base = g * 16;
        const int cnt  = min(16, nflag - base);
        __syncthreads();
        for (int it = 0; it < 2; ++it) {
            int f4 = tid + it * 256;
            int r  = f4 >> 5;
            int d4 = (f4 & 31) * 4;
            int row = ws_list[base + (r < cnt ? r : 0)];
            float4 v = *reinterpret_cast<const float4*>(x + (size_t)row * DIMC + d4);
            xs[d4 + 0][r] = v.x; xs[d4 + 1][r] = v.y;
            xs[d4 + 2][r] = v.z; xs[d4 + 3][r] = v.w;
        }
        __syncthreads();

        float b1[16]; int i1[16];
#pragma unroll
        for (int r = 0; r < 16; ++r) { b1[r] = -3.4e38f; i1[r] = 0; }

        for (int i = 0; i < 16; ++i) {
            int col = tid + i * 256;
            float acc[16];
#pragma unroll
            for (int r = 0; r < 16; ++r) acc[r] = 0.f;
            for (int d = 0; d < DIMC; ++d) {
                float ev = embed[(size_t)d * KC + col];
                float4 xa = *reinterpret_cast<const float4*>(&xs[d][0]);
                float4 xb = *reinterpret_cast<const float4*>(&xs[d][4]);
                float4 xc = *reinterpret_cast<const float4*>(&xs[d][8]);
                float4 xd = *reinterpret_cast<const float4*>(&xs[d][12]);
                acc[0]  = fmaf(xa.x, ev, acc[0]);  acc[1]  = fmaf(xa.y, ev, acc[1]);
                acc[2]  = fmaf(xa.z, ev, acc[2]);  acc[3]  = fmaf(xa.w, ev, acc[3]);
                acc[4]  = fmaf(xb.x, ev, acc[4]);  acc[5]  = fmaf(xb.y, ev, acc[5]);
                acc[6]  = fmaf(xb.z, ev, acc[6]);  acc[7]  = fmaf(xb.w, ev, acc[7]);
                acc[8]  = fmaf(xc.x, ev, acc[8]);  acc[9]  = fmaf(xc.y, ev, acc[9]);
                acc[10] = fmaf(xc.z, ev, acc[10]); acc[11] = fmaf(xc.w, ev, acc[11]);
                acc[12] = fmaf(xd.x, ev, acc[12]); acc[13] = fmaf(xd.y, ev, acc[13]);
                acc[14] = fmaf(xd.z, ev, acc[14]); acc[15] = fmaf(xd.w, ev, acc[15]);
            }
            float nh = nhe2[col];
#pragma unroll
            for (int r = 0; r < 16; ++r) {
                float s = acc[r] + nh;
                if (s > b1[r]) { b1[r] = s; i1[r] = col; }
            }
        }
#pragma unroll
        for (int off = 1; off < 64; off <<= 1)
#pragma unroll
            for (int r = 0; r < 16; ++r) {
                float ob = __shfl_xor(b1[r], off, 64);
                int   oi = __shfl_xor(i1[r], off, 64);
                if (ob > b1[r] || (ob == b1[r] && oi < i1[r])) { b1[r] = ob; i1[r] = oi; }
            }
        if (lane == 0)
#pragma unroll
            for (int r = 0; r < 16; ++r) { redv[wave][r] = b1[r]; redi[wave][r] = i1[r]; }
        __syncthreads();
        if (tid < cnt) {
            float bv = redv[0][tid]; int bi = redi[0][tid];
#pragma unroll
            for (int w = 1; w < 4; ++w) {
                float ov = redv[w][tid]; int oi = redi[w][tid];
                if (ov > bv || (ov == bv && oi < bi)) { bv = ov; bi = oi; }
            }
            int row = ws_list[base + tid];
            ws_ind[row]   = bi;
            out_indf[row] = (float)bi;
        }
    }
}

// ---------------- kernel H: histogram of cluster ids ----------------
__global__ __launch_bounds__(256) void hist_kernel(const int* __restrict__ ind,
                                                   int* __restrict__ cnt) {
    int n = blockIdx.x * 256 + threadIdx.x;
    atomicAdd(&cnt[ind[n]], 1);
}

// ---------------- kernel X: exclusive prefix sum over 4096 counts ----------------
__global__ __launch_bounds__(1024) void scan_kernel(const int* __restrict__ cnt,
                                                    int* __restrict__ start,
                                                    int* __restrict__ cursor) {
    __shared__ int sh[1024];
    const int t = threadIdx.x;
    int4 c = *reinterpret_cast<const int4*>(cnt + t * 4);
    int s = c.x + c.y + c.z + c.w;
    sh[t] = s;
    __syncthreads();
    for (int off = 1; off < 1024; off <<= 1) {
        int v = (t >= off) ? sh[t - off] : 0;
        __syncthreads();
        sh[t] += v;
        __syncthreads();
    }
    int s0 = (t == 0) ? 0 : sh[t - 1];
    start[t * 4 + 0] = s0; cursor[t * 4 + 0] = s0; s0 += c.x;
    start[t * 4 + 1] = s0; cursor[t * 4 + 1] = s0; s0 += c.y;
    start[t * 4 + 2] = s0; cursor[t * 4 + 2] = s0; s0 += c.z;
    start[t * 4 + 3] = s0; cursor[t * 4 + 3] = s0;
}

// ---------------- kernel B: scatter row ids into cluster-sorted order ----------------
__global__ __launch_bounds__(256) void bucket_kernel(const int* __restrict__ ind,
                                                     int* __restrict__ cursor,
                                                     int* __restrict__ sorted) {
    int n = blockIdx.x * 256 + threadIdx.x;
    int p = atomicAdd(&cursor[ind[n]], 1);
    sorted[p] = n;
}

// ---------------- kernel CS v2: per-cluster segmented sum + fused quantize + loss ----------------
// One block per cluster, 128 threads = one lane per d. Row ids staged in LDS;
// 4-deep independent x-loads break the per-iteration latency chain.
__global__ __launch_bounds__(128) void cluster_sum_kernel(
    const float* __restrict__ x, const float* __restrict__ embed,
    const int* __restrict__ sorted, const int* __restrict__ start,
    const int* __restrict__ cnt, float* __restrict__ quant_out,
    float* __restrict__ ws_sum, float* __restrict__ ws_lpart)
{
    const int k = blockIdx.x;
    const int d = threadIdx.x;
    const int s0 = start[k];
    const int c  = cnt[k];
    const float e = embed[(size_t)d * KC + k];   // strided one-time read (L2-hot)
    __shared__ int rows[256];

    float a0 = 0.f, a1 = 0.f, a2 = 0.f, a3 = 0.f;
    float l0 = 0.f, l1 = 0.f, l2 = 0.f, l3 = 0.f;

    for (int base = 0; base < c; base += 256) {
        int m = min(256, c - base);
        __syncthreads();
        if (d < m)        rows[d] = sorted[s0 + base + d];
        if (d + 128 < m)  rows[d + 128] = sorted[s0 + base + d + 128];
        __syncthreads();
        int i = 0;
        for (; i + 4 <= m; i += 4) {
            int r0 = rows[i + 0], r1 = rows[i + 1], r2 = rows[i + 2], r3 = rows[i + 3];
            float x0 = x[(size_t)r0 * DIMC + d];
            float x1 = x[(size_t)r1 * DIMC + d];
            float x2 = x[(size_t)r2 * DIMC + d];
            float x3 = x[(size_t)r3 * DIMC + d];
            float d0 = e - x0, d1 = e - x1, d2 = e - x2, d3 = e - x3;
            a0 += x0; a1 += x1; a2 += x2; a3 += x3;
            l0 = fmaf(d0, d0, l0); l1 = fmaf(d1, d1, l1);
            l2 = fmaf(d2, d2, l2); l3 = fmaf(d3, d3, l3);
            quant_out[(size_t)r0 * DIMC + d] = x0 + d0;   // x + (q-x): matches ref rounding
            quant_out[(size_t)r1 * DIMC + d] = x1 + d1;
            quant_out[(size_t)r2 * DIMC + d] = x2 + d2;
            quant_out[(size_t)r3 * DIMC + d] = x3 + d3;
        }
        for (; i < m; ++i) {
            int r0 = rows[i];
            float x0 = x[(size_t)r0 * DIMC + d];
            float d0 = e - x0;
            a0 += x0;
            l0 = fmaf(d0, d0, l0);
            quant_out[(size_t)r0 * DIMC + d] = x0 + d0;
        }
    }
    float acc  = (a0 + a1) + (a2 + a3);
    float loss = (l0 + l1) + (l2 + l3);
    ws_sum[(size_t)d * KC + k] = acc;

#pragma unroll
    for (int off = 32; off >= 1; off >>= 1) loss += __shfl_down(loss, off, 64);
    __shared__ float red[2];
    if ((d & 63) == 0) red[d >> 6] = loss;
    __syncthreads();
    if (d == 0) ws_lpart[k] = red[0] + red[1];
}

// ---------------- kernel D: cluster_size_new, n_small, loss, inverse norm ----------------
__global__ __launch_bounds__(1024) void finalize_kernel(
    const float* __restrict__ cs, const int* __restrict__ cnt,
    const float* __restrict__ ws_lpart,
    float* __restrict__ out_loss, float* __restrict__ out_nsmall,
    float* __restrict__ out_csn, float* __restrict__ ws_inv)
{
    const int tid = threadIdx.x;
    float csn_loc[4];
    float lsum = 0.f, lsmall = 0.f, lloss = 0.f;
#pragma unroll
    for (int i = 0; i < 4; ++i) {
        int k = tid + i * 1024;
        float csn = cs[k] * DECAYC + OMDECAY * (float)cnt[k];
        out_csn[k] = csn;
        csn_loc[i] = csn;
        lsum += csn;
        lsmall += (csn < 1.f) ? 1.f : 0.f;
        lloss += ws_lpart[k];
    }
#pragma unroll
    for (int off = 32; off >= 1; off >>= 1) {
        lsum   += __shfl_down(lsum, off, 64);
        lsmall += __shfl_down(lsmall, off, 64);
        lloss  += __shfl_down(lloss, off, 64);
    }
    __shared__ float sh1[16], sh2[16], sh3[16];
    __shared__ float ntot_s;
    if ((tid & 63) == 0) { sh1[tid >> 6] = lsum; sh2[tid >> 6] = lsmall; sh3[tid >> 6] = lloss; }
    __syncthreads();
    if (tid == 0) {
        float tot = 0.f, sm = 0.f, lo = 0.f;
        for (int w = 0; w < 16; ++w) { tot += sh1[w]; sm += sh2[w]; lo += sh3[w]; }
        ntot_s = tot;
        out_nsmall[0] = sm;
        out_loss[0] = lo * (1.0f / ((float)NVEC * (float)DIMC));
    }
    __syncthreads();
    float ntot = ntot_s;
    float scale = (ntot + (float)KC * EPSC) / ntot;
#pragma unroll
    for (int i = 0; i < 4; ++i) {
        int k = tid + i * 1024;
        ws_inv[k] = scale / (csn_loc[i] + EPSC);
    }
}

// ---------------- kernel E: embed_avg_new and embed_new ----------------
__global__ __launch_bounds__(256) void ema_embed_kernel(
    const float* __restrict__ ea, const float* __restrict__ ws_sum,
    const float* __restrict__ ws_inv, float* __restrict__ out_embed_new,
    float* __restrict__ out_ean)
{
    size_t i4 = ((size_t)blockIdx.x * 256 + threadIdx.x) * 4;
    float4 a = *reinterpret_cast<const float4*>(ea + i4);
    float4 s = *reinterpret_cast<const float4*>(ws_sum + i4);
    int k = (int)(i4 & (KC - 1));
    float4 inv = *reinterpret_cast<const float4*>(ws_inv + k);
    float e0 = a.x * DECAYC + OMDECAY * s.x;
    float e1 = a.y * DECAYC + OMDECAY * s.y;
    float e2 = a.z * DECAYC + OMDECAY * s.z;
    float e3 = a.w * DECAYC + OMDECAY * s.w;
    // out buffers are 8B- (not 16B-) aligned -> float2 stores
    *reinterpret_cast<float2*>(out_ean + i4)     = make_float2(e0, e1);
    *reinterpret_cast<float2*>(out_ean + i4 + 2) = make_float2(e2, e3);
    *reinterpret_cast<float2*>(out_embed_new + i4)     = make_float2(e0 * inv.x, e1 * inv.y);
    *reinterpret_cast<float2*>(out_embed_new + i4 + 2) = make_float2(e2 * inv.z, e3 * inv.w);
}

extern "C" void kernel_launch(void* const* d_in, const int* in_sizes, int n_in,
                              void* d_out, int out_size, void* d_ws, size_t ws_size,
                              hipStream_t stream) {
    const float* x     = (const float*)d_in[0];   // [N, D]
    const float* embed = (const float*)d_in[1];   // [D, K]
    const float* cs    = (const float*)d_in[2];   // [K]
    const float* ea    = (const float*)d_in[3];   // [D, K]

    float* out  = (float*)d_out;
    float* out0 = out;                 // quantize_st   [N, D]
    float* out1 = out + 16777216;      // quant_loss
    float* out2 = out + 16777217;      // n_small
    float* out3 = out + 16777218;      // embed_ind [N]
    float* out4 = out + 16908290;      // embed_new [D, K]
    float* out5 = out + 17432578;      // cluster_size_new [K]
    float* out6 = out + 17436674;      // embed_avg_new [D, K]

    // workspace layout (float units)
    float* ws       = (float*)d_ws;
    float* ws_sum   = ws;                    // 524288
    int*   ws_nflag = (int*)(ws + 528385);   // 1 (zeroed)
    float* ws_inv   = ws + 528388;           // 4096
    float* nhe2     = ws + 532484;           // 4096
    int*   ws_ind   = (int*)(ws + 1060868);  // 131072
    float* ws_gap   = ws + 1191940;          // 131072
    int*   ws_list  = (int*)(ws + 1323012);  // 131072
    __bf16* ehT     = (__bf16*)(ws + 1454084); // 262144 floats worth of bf16
    __bf16* elT     = (__bf16*)(ws + 1716228);
    // aliases (used only AFTER phase1 is done with ehT/elT):
    int*   ws_sorted = (int*)(ws + 1454084);   // 131072 ints, aliases ehT region
    int*   ws_cnt_i  = (int*)(ws + 1716228);   // 4096 ints,  aliases elT region
    int*   ws_start  = (int*)(ws + 1720324);   // 4096
    int*   ws_cursor = (int*)(ws + 1724420);   // 4096
    float* ws_lpart  = ws + 1728516;           // 4096

    hipMemsetAsync(ws_nflag, 0, sizeof(int), stream);

    hipLaunchKernelGGL(split_e_kernel,   dim3(KC / 64), dim3(256), 0, stream,
                       embed, ehT, elT, nhe2);
    hipLaunchKernelGGL(phase1_kernel,    dim3(NVEC / 256), dim3(256), 0, stream,
                       x, ehT, elT, nhe2, out3, ws_ind, ws_gap);
    hipLaunchKernelGGL(flag_kernel,      dim3(NVEC / 256), dim3(256), 0, stream,
                       ws_gap, ws_nflag, ws_list);
    hipLaunchKernelGGL(rescore_kernel,   dim3(512), dim3(256), 0, stream,
                       x, embed, nhe2, ws_list, ws_nflag, ws_ind, out3);

    // counting sort by cluster id (aliases safe: ehT/elT dead after phase1)
    hipMemsetAsync(ws_cnt_i, 0, KC * sizeof(int), stream);
    hipLaunchKernelGGL(hist_kernel,   dim3(NVEC / 256), dim3(256), 0, stream, ws_ind, ws_cnt_i);
    hipLaunchKernelGGL(scan_kernel,   dim3(1), dim3(1024), 0, stream, ws_cnt_i, ws_start, ws_cursor);
    hipLaunchKernelGGL(bucket_kernel, dim3(NVEC / 256), dim3(256), 0, stream,
                       ws_ind, ws_cursor, ws_sorted);
    hipLaunchKernelGGL(cluster_sum_kernel, dim3(KC), dim3(128), 0, stream,
                       x, embed, ws_sorted, ws_start, ws_cnt_i, out0, ws_sum, ws_lpart);

    hipLaunchKernelGGL(finalize_kernel, dim3(1), dim3(1024), 0, stream,
                       cs, ws_cnt_i, ws_lpart, out1, out2, out5, ws_inv);
    hipLaunchKernelGGL(ema_embed_kernel, dim3((DIMC * KC) / 1024), dim3(256), 0, stream,
                       ea, ws_sum, ws_inv, out4, out6);
}

// Round 5
// 935.891 us; speedup vs baseline: 2.6548x; 2.6548x over previous
//
#include <hip/hip_runtime.h>

// Problem constants (match reference)
constexpr int   NVEC  = 131072;   // N
constexpr int   DIMC  = 128;      // latent dim
constexpr int   KC    = 4096;     // codebook size
constexpr float DECAYC = 0.99f;
constexpr float OMDECAY = 0.01f;
constexpr float EPSC  = 1e-5f;
constexpr float MARGIN = 0.1f;    // >> worst-case split-bf16 score error (~0.02)

typedef __bf16 v8bf __attribute__((ext_vector_type(8)));
typedef float  v4f  __attribute__((ext_vector_type(4)));

// Async global->LDS 16B copy: dest = wave-uniform LDS base + lane*16.
__device__ __forceinline__ void async_copy16(const void* gp, void* lds_wave_base, int lane) {
#if __has_builtin(__builtin_amdgcn_global_load_lds)
    __builtin_amdgcn_global_load_lds(
        (const __attribute__((address_space(1))) unsigned int*)gp,
        (__attribute__((address_space(3))) unsigned int*)lds_wave_base, 16, 0, 0);
#else
    ((v8bf*)lds_wave_base)[lane] = *(const v8bf*)gp;
#endif
}

// ---------------- kernel S: split embed into bf16 hi/lo (transposed) + fused colnorm ----------------
__global__ __launch_bounds__(256) void split_e_kernel(const float* __restrict__ embed,
                                                      __bf16* __restrict__ ehT,
                                                      __bf16* __restrict__ elT,
                                                      float* __restrict__ nhe2) {
    __shared__ __bf16 sh_h[64 * 130];
    __shared__ __bf16 sh_l[64 * 130];
    __shared__ float  sh_n[4][64];
    const int tid = threadIdx.x;
    const int kbase = blockIdx.x * 64;
    const int kloc = tid & 63;
    float nacc = 0.f;
    for (int it = 0; it < 32; ++it) {
        int d = it * 4 + (tid >> 6);
        float v = embed[(size_t)d * KC + kbase + kloc];   // coalesced in k
        __bf16 h = (__bf16)v;
        __bf16 l = (__bf16)(v - (float)h);
        sh_h[kloc * 130 + d] = h;
        sh_l[kloc * 130 + d] = l;
        nacc = fmaf(v, v, nacc);
    }
    sh_n[tid >> 6][kloc] = nacc;
    __syncthreads();
    if (tid < 64)
        nhe2[kbase + tid] = -0.5f * (sh_n[0][tid] + sh_n[1][tid] + sh_n[2][tid] + sh_n[3][tid]);
    for (int it = 0; it < 32; ++it) {
        int idx = it * 256 + tid;
        int k = idx >> 7;
        int d = idx & 127;
        ehT[(size_t)(kbase + k) * DIMC + d] = sh_h[k * 130 + d];
        elT[(size_t)(kbase + k) * DIMC + d] = sh_l[k * 130 + d];
    }
}

// ---------------- kernel P1 v3: MFMA split-bf16 GEMM + per-row top-2 ----------------
// 4 waves/block; wave owns 32 rows (2 x 16-row tiles, A frags = 64 VGPRs — no spill).
// Embed chunk (64 cols x 128 k, hi+lo) in one 32 KB LDS array of 16 B granules,
// XOR-swizzled: granule (col, g) at index col*16 + (g ^ (col&7)).
//  - staging writes (lane-contiguous via global_load_lds) and fragment
//    ds_read_b128 both land 8 words/bank -> conflict-free.
//  - staging source offset per thread is chunk-invariant: pointer += stride.
__global__ __launch_bounds__(256, 2) void phase1_kernel(
    const float* __restrict__ x, const __bf16* __restrict__ ehT,
    const __bf16* __restrict__ elT, const float* __restrict__ nhe2,
    float* __restrict__ out_indf, int* __restrict__ ws_ind, float* __restrict__ ws_gap)
{
    __shared__ v8bf E[2048];    // [0..1023] = hi, [1024..2047] = lo
    const int tid  = threadIdx.x;
    const int wave = tid >> 6;
    const int lane = tid & 63;
    const int c    = lane & 15;     // MFMA m / n index
    const int q    = lane >> 4;     // quad
    const int rowBase = blockIdx.x * 128 + wave * 32;

    // A fragments: 2 row-tiles x 4 k-slices, hi + exact residual lo
    v8bf ah[2][4], al[2][4];
#pragma unroll
    for (int t = 0; t < 2; ++t)
#pragma unroll
        for (int s = 0; s < 4; ++s) {
            const float* p = x + (size_t)(rowBase + t * 16 + c) * DIMC + s * 32 + q * 8;
            float4 v0 = *reinterpret_cast<const float4*>(p);
            float4 v1 = *reinterpret_cast<const float4*>(p + 4);
            float vv[8] = {v0.x, v0.y, v0.z, v0.w, v1.x, v1.y, v1.z, v1.w};
            v8bf h, l;
#pragma unroll
            for (int j = 0; j < 8; ++j) {
                __bf16 hh = (__bf16)vv[j];
                h[j] = hh;
                l[j] = (__bf16)(vv[j] - (float)hh);
            }
            ah[t][s] = h; al[t][s] = l;
        }

    // Staging source pointers (chunk-invariant per-thread offset; advance by stride)
    const int gsw = (tid & 15) ^ ((tid >> 4) & 7);          // source granule within col
    const __bf16* ph = ehT + (size_t)(tid >> 4) * DIMC + gsw * 8;
    const __bf16* pl = elT + (size_t)(tid >> 4) * DIMC + gsw * 8;

    // Per-thread LDS fragment granule indices (ct*256 folds into ds_read offset)
    int gidx[4];
#pragma unroll
    for (int s = 0; s < 4; ++s) gidx[s] = c * 16 + ((s * 4 + q) ^ (c & 7));

    float b1[8], b2[8]; int i1[8];
#pragma unroll
    for (int s = 0; s < 8; ++s) { b1[s] = -3.4e38f; b2[s] = -3.4e38f; i1[s] = 0; }

    for (int chunk = 0; chunk < KC / 64; ++chunk) {
#pragma unroll
        for (int it = 0; it < 4; ++it) {
            async_copy16(ph + (size_t)it * 16 * DIMC, &E[it * 256 + wave * 64], lane);
            async_copy16(pl + (size_t)it * 16 * DIMC, &E[1024 + it * 256 + wave * 64], lane);
        }
        ph += (size_t)64 * DIMC;
        pl += (size_t)64 * DIMC;
        __syncthreads();

#pragma unroll
        for (int ct = 0; ct < 4; ++ct) {
            v4f acc0 = {0.f, 0.f, 0.f, 0.f};
            v4f acc1 = {0.f, 0.f, 0.f, 0.f};
#pragma unroll
            for (int s = 0; s < 4; ++s) {
                v8bf bh = E[ct * 256 + gidx[s]];
                v8bf bl = E[1024 + ct * 256 + gidx[s]];
                acc0 = __builtin_amdgcn_mfma_f32_16x16x32_bf16(ah[0][s], bh, acc0, 0, 0, 0);
                acc1 = __builtin_amdgcn_mfma_f32_16x16x32_bf16(ah[1][s], bh, acc1, 0, 0, 0);
                acc0 = __builtin_amdgcn_mfma_f32_16x16x32_bf16(al[0][s], bh, acc0, 0, 0, 0);
                acc1 = __builtin_amdgcn_mfma_f32_16x16x32_bf16(al[1][s], bh, acc1, 0, 0, 0);
                acc0 = __builtin_amdgcn_mfma_f32_16x16x32_bf16(ah[0][s], bl, acc0, 0, 0, 0);
                acc1 = __builtin_amdgcn_mfma_f32_16x16x32_bf16(ah[1][s], bl, acc1, 0, 0, 0);
            }
            const int colG = chunk * 64 + ct * 16 + c;
            const float nh = nhe2[colG];
#pragma unroll
            for (int r = 0; r < 4; ++r) {
                float sc = acc0[r] + nh;
                float ob = b1[r];
                b2[r] = __builtin_amdgcn_fmed3f(ob, b2[r], sc);  // exact 2nd-best update
                b1[r] = fmaxf(ob, sc);
                i1[r] = (sc > ob) ? colG : i1[r];                 // strict: tie keeps earlier col
                float sc1 = acc1[r] + nh;
                float ob1 = b1[4 + r];
                b2[4 + r] = __builtin_amdgcn_fmed3f(ob1, b2[4 + r], sc1);
                b1[4 + r] = fmaxf(ob1, sc1);
                i1[4 + r] = (sc1 > ob1) ? colG : i1[4 + r];
            }
        }
        __syncthreads();
    }

    // top-2 merge across the 16 col-lanes of each row group (tie -> lowest index)
#pragma unroll
    for (int off = 1; off < 16; off <<= 1) {
#pragma unroll
        for (int s = 0; s < 8; ++s) {
            float ob1 = __shfl_xor(b1[s], off, 64);
            int   oi1 = __shfl_xor(i1[s], off, 64);
            float ob2 = __shfl_xor(b2[s], off, 64);
            if (ob1 > b1[s] || (ob1 == b1[s] && oi1 < i1[s])) {
                b2[s] = fmaxf(b1[s], ob2); b1[s] = ob1; i1[s] = oi1;
            } else {
                b2[s] = fmaxf(b2[s], ob1);
            }
        }
    }
    if (c == 0) {
#pragma unroll
        for (int s = 0; s < 8; ++s) {
            int t = s >> 2, r = s & 3;
            int row = rowBase + t * 16 + q * 4 + r;
            ws_ind[row]   = i1[s];
            out_indf[row] = (float)i1[s];
            ws_gap[row]   = b1[s] - b2[s];
        }
    }
}

// ---------------- kernel F: compact flagged rows (gap < MARGIN) ----------------
__global__ __launch_bounds__(256) void flag_kernel(const float* __restrict__ ws_gap,
                                                   int* __restrict__ ws_nflag,
                                                   int* __restrict__ ws_list) {
    int n = blockIdx.x * 256 + threadIdx.x;
    if (ws_gap[n] < MARGIN) {
        int p = atomicAdd(ws_nflag, 1);
        ws_list[p] = n;
    }
}

// ---------------- kernel R: exact fp32 rescore of flagged rows (16 rows/block) ----------------
__global__ __launch_bounds__(256) void rescore_kernel(
    const float* __restrict__ x, const float* __restrict__ embed,
    const float* __restrict__ nhe2, const int* __restrict__ ws_list,
    const int* __restrict__ ws_nflag, int* __restrict__ ws_ind,
    float* __restrict__ out_indf)
{
    __shared__ float xs[128][16];
    __shared__ float redv[4][16];
    __shared__ int   redi[4][16];
    const int tid  = threadIdx.x;
    const int lane = tid & 63;
    const int wave = tid >> 6;
    const int nflag = *ws_nflag;

    for (int g = blockIdx.x; g * 16 < nflag; g += gridDim.x) {
        const int base = g * 16;
        const int cnt  = min(16, nflag - base);
        __syncthreads();
        for (int it = 0; it < 2; ++it) {
            int f4 = tid + it * 256;
            int r  = f4 >> 5;
            int d4 = (f4 & 31) * 4;
            int row = ws_list[base + (r < cnt ? r : 0)];
            float4 v = *reinterpret_cast<const float4*>(x + (size_t)row * DIMC + d4);
            xs[d4 + 0][r] = v.x; xs[d4 + 1][r] = v.y;
            xs[d4 + 2][r] = v.z; xs[d4 + 3][r] = v.w;
        }
        __syncthreads();

        float b1[16]; int i1[16];
#pragma unroll
        for (int r = 0; r < 16; ++r) { b1[r] = -3.4e38f; i1[r] = 0; }

        for (int i = 0; i < 16; ++i) {
            int col = tid + i * 256;
            float acc[16];
#pragma unroll
            for (int r = 0; r < 16; ++r) acc[r] = 0.f;
            for (int d = 0; d < DIMC; ++d) {
                float ev = embed[(size_t)d * KC + col];
                float4 xa = *reinterpret_cast<const float4*>(&xs[d][0]);
                float4 xb = *reinterpret_cast<const float4*>(&xs[d][4]);
                float4 xc = *reinterpret_cast<const float4*>(&xs[d][8]);
                float4 xd = *reinterpret_cast<const float4*>(&xs[d][12]);
                acc[0]  = fmaf(xa.x, ev, acc[0]);  acc[1]  = fmaf(xa.y, ev, acc[1]);
                acc[2]  = fmaf(xa.z, ev, acc[2]);  acc[3]  = fmaf(xa.w, ev, acc[3]);
                acc[4]  = fmaf(xb.x, ev, acc[4]);  acc[5]  = fmaf(xb.y, ev, acc[5]);
                acc[6]  = fmaf(xb.z, ev, acc[6]);  acc[7]  = fmaf(xb.w, ev, acc[7]);
                acc[8]  = fmaf(xc.x, ev, acc[8]);  acc[9]  = fmaf(xc.y, ev, acc[9]);
                acc[10] = fmaf(xc.z, ev, acc[10]); acc[11] = fmaf(xc.w, ev, acc[11]);
                acc[12] = fmaf(xd.x, ev, acc[12]); acc[13] = fmaf(xd.y, ev, acc[13]);
                acc[14] = fmaf(xd.z, ev, acc[14]); acc[15] = fmaf(xd.w, ev, acc[15]);
            }
            float nh = nhe2[col];
#pragma unroll
            for (int r = 0; r < 16; ++r) {
                float s = acc[r] + nh;
                if (s > b1[r]) { b1[r] = s; i1[r] = col; }
            }
        }
#pragma unroll
        for (int off = 1; off < 64; off <<= 1)
#pragma unroll
            for (int r = 0; r < 16; ++r) {
                float ob = __shfl_xor(b1[r], off, 64);
                int   oi = __shfl_xor(i1[r], off, 64);
                if (ob > b1[r] || (ob == b1[r] && oi < i1[r])) { b1[r] = ob; i1[r] = oi; }
            }
        if (lane == 0)
#pragma unroll
            for (int r = 0; r < 16; ++r) { redv[wave][r] = b1[r]; redi[wave][r] = i1[r]; }
        __syncthreads();
        if (tid < cnt) {
            float bv = redv[0][tid]; int bi = redi[0][tid];
#pragma unroll
            for (int w = 1; w < 4; ++w) {
                float ov = redv[w][tid]; int oi = redi[w][tid];
                if (ov > bv || (ov == bv && oi < bi)) { bv = ov; bi = oi; }
            }
            int row = ws_list[base + tid];
            ws_ind[row]   = bi;
            out_indf[row] = (float)bi;
        }
    }
}

// ---------------- kernel H: histogram of cluster ids ----------------
__global__ __launch_bounds__(256) void hist_kernel(const int* __restrict__ ind,
                                                   int* __restrict__ cnt) {
    int n = blockIdx.x * 256 + threadIdx.x;
    atomicAdd(&cnt[ind[n]], 1);
}

// ---------------- kernel X: exclusive prefix sum over 4096 counts ----------------
__global__ __launch_bounds__(1024) void scan_kernel(const int* __restrict__ cnt,
                                                    int* __restrict__ start,
                                                    int* __restrict__ cursor) {
    __shared__ int sh[1024];
    const int t = threadIdx.x;
    int4 c = *reinterpret_cast<const int4*>(cnt + t * 4);
    int s = c.x + c.y + c.z + c.w;
    sh[t] = s;
    __syncthreads();
    for (int off = 1; off < 1024; off <<= 1) {
        int v = (t >= off) ? sh[t - off] : 0;
        __syncthreads();
        sh[t] += v;
        __syncthreads();
    }
    int s0 = (t == 0) ? 0 : sh[t - 1];
    start[t * 4 + 0] = s0; cursor[t * 4 + 0] = s0; s0 += c.x;
    start[t * 4 + 1] = s0; cursor[t * 4 + 1] = s0; s0 += c.y;
    start[t * 4 + 2] = s0; cursor[t * 4 + 2] = s0; s0 += c.z;
    start[t * 4 + 3] = s0; cursor[t * 4 + 3] = s0;
}

// ---------------- kernel B: scatter row ids into cluster-sorted order ----------------
__global__ __launch_bounds__(256) void bucket_kernel(const int* __restrict__ ind,
                                                     int* __restrict__ cursor,
                                                     int* __restrict__ sorted) {
    int n = blockIdx.x * 256 + threadIdx.x;
    int p = atomicAdd(&cursor[ind[n]], 1);
    sorted[p] = n;
}

// ---------------- kernel CS v2: per-cluster segmented sum + fused quantize + loss ----------------
__global__ __launch_bounds__(128) void cluster_sum_kernel(
    const float* __restrict__ x, const float* __restrict__ embed,
    const int* __restrict__ sorted, const int* __restrict__ start,
    const int* __restrict__ cnt, float* __restrict__ quant_out,
    float* __restrict__ ws_sum, float* __restrict__ ws_lpart)
{
    const int k = blockIdx.x;
    const int d = threadIdx.x;
    const int s0 = start[k];
    const int c  = cnt[k];
    const float e = embed[(size_t)d * KC + k];
    __shared__ int rows[256];

    float a0 = 0.f, a1 = 0.f, a2 = 0.f, a3 = 0.f;
    float l0 = 0.f, l1 = 0.f, l2 = 0.f, l3 = 0.f;

    for (int base = 0; base < c; base += 256) {
        int m = min(256, c - base);
        __syncthreads();
        if (d < m)        rows[d] = sorted[s0 + base + d];
        if (d + 128 < m)  rows[d + 128] = sorted[s0 + base + d + 128];
        __syncthreads();
        int i = 0;
        for (; i + 4 <= m; i += 4) {
            int r0 = rows[i + 0], r1 = rows[i + 1], r2 = rows[i + 2], r3 = rows[i + 3];
            float x0 = x[(size_t)r0 * DIMC + d];
            float x1 = x[(size_t)r1 * DIMC + d];
            float x2 = x[(size_t)r2 * DIMC + d];
            float x3 = x[(size_t)r3 * DIMC + d];
            float d0 = e - x0, d1 = e - x1, d2 = e - x2, d3 = e - x3;
            a0 += x0; a1 += x1; a2 += x2; a3 += x3;
            l0 = fmaf(d0, d0, l0); l1 = fmaf(d1, d1, l1);
            l2 = fmaf(d2, d2, l2); l3 = fmaf(d3, d3, l3);
            quant_out[(size_t)r0 * DIMC + d] = x0 + d0;
            quant_out[(size_t)r1 * DIMC + d] = x1 + d1;
            quant_out[(size_t)r2 * DIMC + d] = x2 + d2;
            quant_out[(size_t)r3 * DIMC + d] = x3 + d3;
        }
        for (; i < m; ++i) {
            int r0 = rows[i];
            float x0 = x[(size_t)r0 * DIMC + d];
            float d0 = e - x0;
            a0 += x0;
            l0 = fmaf(d0, d0, l0);
            quant_out[(size_t)r0 * DIMC + d] = x0 + d0;
        }
    }
    float acc  = (a0 + a1) + (a2 + a3);
    float loss = (l0 + l1) + (l2 + l3);
    ws_sum[(size_t)d * KC + k] = acc;

#pragma unroll
    for (int off = 32; off >= 1; off >>= 1) loss += __shfl_down(loss, off, 64);
    __shared__ float red[2];
    if ((d & 63) == 0) red[d >> 6] = loss;
    __syncthreads();
    if (d == 0) ws_lpart[k] = red[0] + red[1];
}

// ---------------- kernel D: cluster_size_new, n_small, loss, inverse norm ----------------
__global__ __launch_bounds__(1024) void finalize_kernel(
    const float* __restrict__ cs, const int* __restrict__ cnt,
    const float* __restrict__ ws_lpart,
    float* __restrict__ out_loss, float* __restrict__ out_nsmall,
    float* __restrict__ out_csn, float* __restrict__ ws_inv)
{
    const int tid = threadIdx.x;
    float csn_loc[4];
    float lsum = 0.f, lsmall = 0.f, lloss = 0.f;
#pragma unroll
    for (int i = 0; i < 4; ++i) {
        int k = tid + i * 1024;
        float csn = cs[k] * DECAYC + OMDECAY * (float)cnt[k];
        out_csn[k] = csn;
        csn_loc[i] = csn;
        lsum += csn;
        lsmall += (csn < 1.f) ? 1.f : 0.f;
        lloss += ws_lpart[k];
    }
#pragma unroll
    for (int off = 32; off >= 1; off >>= 1) {
        lsum   += __shfl_down(lsum, off, 64);
        lsmall += __shfl_down(lsmall, off, 64);
        lloss  += __shfl_down(lloss, off, 64);
    }
    __shared__ float sh1[16], sh2[16], sh3[16];
    __shared__ float ntot_s;
    if ((tid & 63) == 0) { sh1[tid >> 6] = lsum; sh2[tid >> 6] = lsmall; sh3[tid >> 6] = lloss; }
    __syncthreads();
    if (tid == 0) {
        float tot = 0.f, sm = 0.f, lo = 0.f;
        for (int w = 0; w < 16; ++w) { tot += sh1[w]; sm += sh2[w]; lo += sh3[w]; }
        ntot_s = tot;
        out_nsmall[0] = sm;
        out_loss[0] = lo * (1.0f / ((float)NVEC * (float)DIMC));
    }
    __syncthreads();
    float ntot = ntot_s;
    float scale = (ntot + (float)KC * EPSC) / ntot;
#pragma unroll
    for (int i = 0; i < 4; ++i) {
        int k = tid + i * 1024;
        ws_inv[k] = scale / (csn_loc[i] + EPSC);
    }
}

// ---------------- kernel E: embed_avg_new and embed_new ----------------
__global__ __launch_bounds__(256) void ema_embed_kernel(
    const float* __restrict__ ea, const float* __restrict__ ws_sum,
    const float* __restrict__ ws_inv, float* __restrict__ out_embed_new,
    float* __restrict__ out_ean)
{
    size_t i4 = ((size_t)blockIdx.x * 256 + threadIdx.x) * 4;
    float4 a = *reinterpret_cast<const float4*>(ea + i4);
    float4 s = *reinterpret_cast<const float4*>(ws_sum + i4);
    int k = (int)(i4 & (KC - 1));
    float4 inv = *reinterpret_cast<const float4*>(ws_inv + k);
    float e0 = a.x * DECAYC + OMDECAY * s.x;
    float e1 = a.y * DECAYC + OMDECAY * s.y;
    float e2 = a.z * DECAYC + OMDECAY * s.z;
    float e3 = a.w * DECAYC + OMDECAY * s.w;
    *reinterpret_cast<float2*>(out_ean + i4)     = make_float2(e0, e1);
    *reinterpret_cast<float2*>(out_ean + i4 + 2) = make_float2(e2, e3);
    *reinterpret_cast<float2*>(out_embed_new + i4)     = make_float2(e0 * inv.x, e1 * inv.y);
    *reinterpret_cast<float2*>(out_embed_new + i4 + 2) = make_float2(e2 * inv.z, e3 * inv.w);
}

extern "C" void kernel_launch(void* const* d_in, const int* in_sizes, int n_in,
                              void* d_out, int out_size, void* d_ws, size_t ws_size,
                              hipStream_t stream) {
    const float* x     = (const float*)d_in[0];   // [N, D]
    const float* embed = (const float*)d_in[1];   // [D, K]
    const float* cs    = (const float*)d_in[2];   // [K]
    const float* ea    = (const float*)d_in[3];   // [D, K]

    float* out  = (float*)d_out;
    float* out0 = out;                 // quantize_st   [N, D]
    float* out1 = out + 16777216;      // quant_loss
    float* out2 = out + 16777217;      // n_small
    float* out3 = out + 16777218;      // embed_ind [N]
    float* out4 = out + 16908290;      // embed_new [D, K]
    float* out5 = out + 17432578;      // cluster_size_new [K]
    float* out6 = out + 17436674;      // embed_avg_new [D, K]

    // workspace layout (float units)
    float* ws       = (float*)d_ws;
    float* ws_sum   = ws;                    // 524288
    int*   ws_nflag = (int*)(ws + 528385);   // 1 (zeroed)
    float* ws_inv   = ws + 528388;           // 4096
    float* nhe2     = ws + 532484;           // 4096
    int*   ws_ind   = (int*)(ws + 1060868);  // 131072
    float* ws_gap   = ws + 1191940;          // 131072
    int*   ws_list  = (int*)(ws + 1323012);  // 131072
    __bf16* ehT     = (__bf16*)(ws + 1454084);
    __bf16* elT     = (__bf16*)(ws + 1716228);
    // aliases (used only AFTER phase1 is done with ehT/elT):
    int*   ws_sorted = (int*)(ws + 1454084);
    int*   ws_cnt_i  = (int*)(ws + 1716228);
    int*   ws_start  = (int*)(ws + 1720324);
    int*   ws_cursor = (int*)(ws + 1724420);
    float* ws_lpart  = ws + 1728516;

    hipMemsetAsync(ws_nflag, 0, sizeof(int), stream);

    hipLaunchKernelGGL(split_e_kernel,   dim3(KC / 64), dim3(256), 0, stream,
                       embed, ehT, elT, nhe2);
    hipLaunchKernelGGL(phase1_kernel,    dim3(NVEC / 128), dim3(256), 0, stream,
                       x, ehT, elT, nhe2, out3, ws_ind, ws_gap);
    hipLaunchKernelGGL(flag_kernel,      dim3(NVEC / 256), dim3(256), 0, stream,
                       ws_gap, ws_nflag, ws_list);
    hipLaunchKernelGGL(rescore_kernel,   dim3(512), dim3(256), 0, stream,
                       x, embed, nhe2, ws_list, ws_nflag, ws_ind, out3);

    // counting sort by cluster id (aliases safe: ehT/elT dead after phase1)
    hipMemsetAsync(ws_cnt_i, 0, KC * sizeof(int), stream);
    hipLaunchKernelGGL(hist_kernel,   dim3(NVEC / 256), dim3(256), 0, stream, ws_ind, ws_cnt_i);
    hipLaunchKernelGGL(scan_kernel,   dim3(1), dim3(1024), 0, stream, ws_cnt_i, ws_start, ws_cursor);
    hipLaunchKernelGGL(bucket_kernel, dim3(NVEC / 256), dim3(256), 0, stream,
                       ws_ind, ws_cursor, ws_sorted);
    hipLaunchKernelGGL(cluster_sum_kernel, dim3(KC), dim3(128), 0, stream,
                       x, embed, ws_sorted, ws_start, ws_cnt_i, out0, ws_sum, ws_lpart);

    hipLaunchKernelGGL(finalize_kernel, dim3(1), dim3(1024), 0, stream,
                       cs, ws_cnt_i, ws_lpart, out1, out2, out5, ws_inv);
    hipLaunchKernelGGL(ema_embed_kernel, dim3((DIMC * KC) / 1024), dim3(256), 0, stream,
                       ea, ws_sum, ws_inv, out4, out6);
}